// Round 3
// baseline (402.252 us; speedup 1.0000x reference)
//
#include <hip/hip_runtime.h>

typedef _Float16 half8 __attribute__((ext_vector_type(8)));
typedef _Float16 half4 __attribute__((ext_vector_type(4)));
typedef float f32x4 __attribute__((ext_vector_type(4)));

#define SA 320           // LDS act stride in halves (40 chunks of 8); 64*320*2 = 40960 B
#define NROW 64          // rows per block = 16 queries x 4 shifts

// ---------------------------------------------------------------------------
// Prep: features -> featT [px][32] fp16 (coalesced transpose);
// weights -> Wt[n][k] fp16. W1 cols permuted col=k*32+c (k=3x3 tap, c=chan);
// cols 288..291 = rel/cell rows of w1; 292..319 = 0.
// ---------------------------------------------------------------------------
__global__ void liif_prep(const float* __restrict__ feat,
                          const float* __restrict__ w1, const float* __restrict__ w2,
                          const float* __restrict__ w3, const float* __restrict__ w4,
                          const float* __restrict__ w5,
                          _Float16* __restrict__ featT,
                          _Float16* __restrict__ wt1, _Float16* __restrict__ wt2,
                          _Float16* __restrict__ wt3, _Float16* __restrict__ wt4,
                          _Float16* __restrict__ wt5) {
  const int blk = blockIdx.x, tid = threadIdx.x;
  if (blk < 256) {                         // featT: thread = 1 px, 64 B contig write
    const int px = blk * 256 + tid;
    _Float16 v[32];
#pragma unroll
    for (int c = 0; c < 32; ++c) v[c] = (_Float16)feat[(c << 16) + px];
    half8* dst = (half8*)(featT + px * 32);
#pragma unroll
    for (int j = 0; j < 4; ++j) dst[j] = *(half8*)(v + j * 8);
    return;
  }
  int i = (blk - 256) * 256 + tid;
  if (i < 81920) {                         // wt1: [256][320]
    const int n = i / 320, kcol = i % 320;
    float v = 0.f;
    if (kcol < 288) {
      const int k = kcol >> 5, c = kcol & 31;
      v = w1[(c * 9 + k) * 256 + n];
    } else if (kcol < 292) {
      v = w1[kcol * 256 + n];
    }
    wt1[i] = (_Float16)v;
    return;
  }
  i -= 81920;
  if (i < 196608) {                        // wt2..wt4: [256][256]
    const int li = i >> 16, r = i & 65535;
    const int n = r >> 8, k = r & 255;
    const float* w = (li == 0) ? w2 : ((li == 1) ? w3 : w4);
    _Float16* wt = (li == 0) ? wt2 : ((li == 1) ? wt3 : wt4);
    wt[r] = (_Float16)w[k * 256 + n];
    return;
  }
  i -= 196608;
  if (i < 4096) {                          // wt5: [16][256], rows 3..15 zero
    const int n = i >> 8, k = i & 255;
    wt5[i] = (n < 3) ? (_Float16)w5[k * 3 + n] : (_Float16)0.f;
  }
}

// ---------------------------------------------------------------------------
// One layer: acc[mt][nt] += Wt-frag (A, m=feature) x act-frag (B, n=queryrow).
// A streams from global/L2 (imm-offset b128), B from swizzled LDS.
// D layout: row = feature = q4+reg, col = queryrow = ln  (m89 mapping).
// ---------------------------------------------------------------------------
template <int NSTEPS, int KW>
__device__ __forceinline__ void layer_mm(const _Float16* __restrict__ wt,
                                         f32x4 acc[4][4],
                                         const _Float16* sA, int w, int lane) {
  const int ln = lane & 15, qd = lane >> 4, e = ln & 7;
  const _Float16* ab[4];
  const _Float16* bb[4];
#pragma unroll
  for (int mt = 0; mt < 4; ++mt)
    ab[mt] = wt + (w * 64 + mt * 16 + ln) * KW + qd * 8;
#pragma unroll
  for (int nt = 0; nt < 4; ++nt)
    bb[nt] = sA + (nt * 16 + ln) * SA;      // (nt*16+ln)&7 == ln&7
#pragma unroll
  for (int st = 0; st < NSTEPS; ++st) {
    const int off = ((((st << 2) | qd) ^ e) << 3);
    half8 a[4], b[4];
#pragma unroll
    for (int mt = 0; mt < 4; ++mt) a[mt] = *(const half8*)(ab[mt] + st * 32);
#pragma unroll
    for (int nt = 0; nt < 4; ++nt) b[nt] = *(const half8*)(bb[nt] + off);
#pragma unroll
    for (int mt = 0; mt < 4; ++mt)
#pragma unroll
      for (int nt = 0; nt < 4; ++nt)
        acc[mt][nt] =
            __builtin_amdgcn_mfma_f32_16x16x32_f16(a[mt], b[nt], acc[mt][nt], 0, 0, 0);
  }
}

// bias + ReLU, write act back (in-place) as half4 b64 stores, swizzled.
__device__ __forceinline__ void epilogue_relu(f32x4 acc[4][4], _Float16* sA,
                                              const float* __restrict__ bias,
                                              int w, int lane) {
  __syncthreads();                          // all waves done reading this layer's act
  const int ln = lane & 15, q4 = (lane >> 4) << 2;
#pragma unroll
  for (int mt = 0; mt < 4; ++mt) {
    const int f = w * 64 + mt * 16 + q4;    // 4 consecutive output features
    const f32x4 bv = *(const f32x4*)(bias + f);
    const int chunk = f >> 3;               // 8-col chunk index (0..31)
#pragma unroll
    for (int nt = 0; nt < 4; ++nt) {
      const int row = nt * 16 + ln;
      half4 h;
#pragma unroll
      for (int r = 0; r < 4; ++r) {
        h[r] = (_Float16)fmaxf(acc[mt][nt][r] + bv[r], 0.f);
        acc[mt][nt][r] = 0.f;
      }
      const int pos = chunk ^ (row & 7);
      *(half4*)(sA + row * SA + pos * 8 + (f & 7)) = h;
    }
  }
  __syncthreads();                          // next layer reads after all writes
}

// ---------------------------------------------------------------------------
// Main fused kernel: 1 block = 64 rows; LDS = act buffer ONLY (40960 B).
// ---------------------------------------------------------------------------
__global__ __launch_bounds__(256, 4) void liif_main(
    const _Float16* __restrict__ featT,
    const float* __restrict__ loc, const float* __restrict__ cell,
    const float* __restrict__ b1, const float* __restrict__ b2,
    const float* __restrict__ b3, const float* __restrict__ b4,
    const float* __restrict__ b5,
    const _Float16* __restrict__ wt1, const _Float16* __restrict__ wt2,
    const _Float16* __restrict__ wt3, const _Float16* __restrict__ wt4,
    const _Float16* __restrict__ wt5,
    float* __restrict__ out) {
  __shared__ __align__(16) _Float16 sAct[NROW * SA];

  const int tid = threadIdx.x;
  const int w = tid >> 6, lane = tid & 63;
  const int blk = blockIdx.x;

  // ---- per-row params: every wave computes all 64 rows (lane l <-> row l) ----
  int iy, ix;
  float rel0v, rel1v, c0v, c1v, wgt;
  {
    const int r = blk * 64 + lane, q = r >> 2, s = r & 3;
    const float loc0 = loc[q * 2 + 0], loc1 = loc[q * 2 + 1];
    const float shy = (s & 2) ? 1.f : -1.f;
    const float shx = (s & 1) ? 1.f : -1.f;
    const float rxy = 1.f / 256.f;
    float l0 = __fadd_rn(loc0 + shy * rxy, 1e-6f);
    float l1 = __fadd_rn(loc1 + shx * rxy, 1e-6f);
    const float lo = -1.f + 1e-6f, hi = 1.f - 1e-6f;
    l0 = fminf(fmaxf(l0, lo), hi);
    l1 = fminf(fmaxf(l1, lo), hi);
    iy = (int)rintf(__fmul_rn(__fadd_rn(__fmul_rn(__fadd_rn(l0, 1.f), 256.f), -1.f), 0.5f));
    ix = (int)rintf(__fmul_rn(__fadd_rn(__fmul_rn(__fadd_rn(l1, 1.f), 256.f), -1.f), 0.5f));
    iy = min(max(iy, 0), 255);
    ix = min(max(ix, 0), 255);
    const float qy = -1.f + (float)(2 * iy + 1) * (1.f / 256.f);
    const float qx = -1.f + (float)(2 * ix + 1) * (1.f / 256.f);
    rel0v = __fmul_rn(__fsub_rn(loc0, qy), 256.f);
    rel1v = __fmul_rn(__fsub_rn(loc1, qx), 256.f);
    c0v = cell[q * 2 + 0] * 256.f;
    c1v = cell[q * 2 + 1] * 256.f;
    const float area = fabsf(rel0v * rel1v) + 1e-9f;
    float t = area + __shfl_xor(area, 1);
    const float tot = t + __shfl_xor(t, 2);
    const float asw = __shfl_xor(area, 3);  // area[q*4 + (3-s)]
    wgt = asw / tot;
  }

  // ---- gather: wave w fills rows w*16..w*16+15; lane=(rl,part) ----
  {
    const int rl = w * 16 + (lane >> 2), part = lane & 3;
    const int giy = __shfl(iy, rl), gix = __shfl(ix, rl);
    const int y0 = (giy == 0) ? 1 : giy - 1;
    const int y2 = (giy == 255) ? 254 : giy + 1;
    const int x0 = (gix == 0) ? 1 : gix - 1;
    const int x2 = (gix == 255) ? 254 : gix + 1;
    _Float16* arow = sAct + rl * SA;
    const int eor = rl & 7;
#pragma unroll
    for (int k = 0; k < 9; ++k) {
      const int dy = k / 3, dx = k % 3;
      const int y = (dy == 0) ? y0 : ((dy == 1) ? giy : y2);
      const int x = (dx == 0) ? x0 : ((dx == 1) ? gix : x2);
      const half8 v = *(const half8*)(featT + ((y << 8) + x) * 32 + part * 8);
      const int pos = (k * 4 + part) ^ eor;
      *(half8*)(arow + pos * 8) = v;
    }
    // tail chunks 36..39 (cols 288..319): rel/cell + zero pad
    const float r0s = __shfl(rel0v, rl), r1s = __shfl(rel1v, rl);
    const float c0s = __shfl(c0v, rl),  c1s = __shfl(c1v, rl);
    half8 tv = {};
    if (part == 0) {
      tv[0] = (_Float16)r0s;
      tv[1] = (_Float16)r1s;
      tv[2] = (_Float16)c0s;
      tv[3] = (_Float16)c1s;
    }
    const int pos = (36 + part) ^ eor;
    *(half8*)(arow + pos * 8) = tv;
  }

  f32x4 acc[4][4];
#pragma unroll
  for (int mt = 0; mt < 4; ++mt)
#pragma unroll
    for (int nt = 0; nt < 4; ++nt)
      acc[mt][nt] = (f32x4){0.f, 0.f, 0.f, 0.f};

  __syncthreads();

  // ---- MLP: layers 1..4 (256-wide, ReLU) ----
  layer_mm<10, 320>(wt1, acc, sAct, w, lane);
  epilogue_relu(acc, sAct, b1, w, lane);
  layer_mm<8, 256>(wt2, acc, sAct, w, lane);
  epilogue_relu(acc, sAct, b2, w, lane);
  layer_mm<8, 256>(wt3, acc, sAct, w, lane);
  epilogue_relu(acc, sAct, b3, w, lane);
  layer_mm<8, 256>(wt4, acc, sAct, w, lane);
  epilogue_relu(acc, sAct, b4, w, lane);

  // ---- layer 5 (16x256, wave-local queries) + area combine, no LDS ----
  {
    const int ln = lane & 15, qd = lane >> 4, e = ln & 7;
    f32x4 a5 = {0.f, 0.f, 0.f, 0.f};
    const _Float16* ab = wt5 + ln * 256 + qd * 8;
    const _Float16* bb = sAct + (w * 16 + ln) * SA;   // (w*16+ln)&7 == ln&7
#pragma unroll
    for (int st = 0; st < 8; ++st) {
      const int off = ((((st << 2) | qd) ^ e) << 3);
      const half8 a = *(const half8*)(ab + st * 32);
      const half8 b = *(const half8*)(bb + off);
      a5 = __builtin_amdgcn_mfma_f32_16x16x32_f16(a, b, a5, 0, 0, 0);
    }
    // lane (ln,qd) reg r holds pred[f=qd*4+r][row=w*16+ln]; real f only 0..2
    const float wr = __shfl(wgt, w * 16 + ln);
    float v0 = (a5[0] + b5[0]) * wr;
    float v1 = (a5[1] + b5[1]) * wr;
    float v2 = (a5[2] + b5[2]) * wr;
    v0 += __shfl_xor(v0, 1); v0 += __shfl_xor(v0, 2);
    v1 += __shfl_xor(v1, 1); v1 += __shfl_xor(v1, 2);
    v2 += __shfl_xor(v2, 1); v2 += __shfl_xor(v2, 2);
    if (qd == 0 && (ln & 3) == 0) {
      const int q = blk * 16 + w * 4 + (ln >> 2);
      out[q * 3 + 0] = v0;
      out[q * 3 + 1] = v1;
      out[q * 3 + 2] = v2;
    }
  }
}

// ---------------------------------------------------------------------------
extern "C" void kernel_launch(void* const* d_in, const int* in_sizes, int n_in,
                              void* d_out, int out_size, void* d_ws, size_t ws_size,
                              hipStream_t stream) {
  (void)in_sizes; (void)n_in; (void)out_size; (void)ws_size;
  const float* feat = (const float*)d_in[0];
  const float* loc  = (const float*)d_in[1];
  const float* cell = (const float*)d_in[2];
  const float* w1 = (const float*)d_in[3];  const float* b1 = (const float*)d_in[4];
  const float* w2 = (const float*)d_in[5];  const float* b2 = (const float*)d_in[6];
  const float* w3 = (const float*)d_in[7];  const float* b3 = (const float*)d_in[8];
  const float* w4 = (const float*)d_in[9];  const float* b4 = (const float*)d_in[10];
  const float* w5 = (const float*)d_in[11]; const float* b5 = (const float*)d_in[12];

  char* ws = (char*)d_ws;
  _Float16* featT = (_Float16*)(ws);                    // 4,194,304 B
  _Float16* wt1 = (_Float16*)(ws + 4194304);            //   163,840 B [256][320]
  _Float16* wt2 = (_Float16*)(ws + 4358144);            //   131,072 B [256][256]
  _Float16* wt3 = (_Float16*)(ws + 4489216);            //   131,072 B
  _Float16* wt4 = (_Float16*)(ws + 4620288);            //   131,072 B
  _Float16* wt5 = (_Float16*)(ws + 4751360);            //     8,192 B [16][256]

  liif_prep<<<1360, 256, 0, stream>>>(feat, w1, w2, w3, w4, w5,
                                      featT, wt1, wt2, wt3, wt4, wt5);
  liif_main<<<4096, 256, 0, stream>>>(featT, loc, cell, b1, b2, b3, b4, b5,
                                      wt1, wt2, wt3, wt4, wt5, (float*)d_out);
}

// Round 4
// 246.074 us; speedup vs baseline: 1.6347x; 1.6347x over previous
//
#include <hip/hip_runtime.h>

typedef _Float16 half8 __attribute__((ext_vector_type(8)));
typedef _Float16 half4 __attribute__((ext_vector_type(4)));
typedef float f32x4 __attribute__((ext_vector_type(4)));

#define SA 320           // LDS act stride in halves (40 chunks of 8)
#define MROW 128         // rows per block = 32 queries x 4 shifts
// LDS act buffer: 128*320*2 = 81920 B -> exactly 2 blocks/CU

// ---------------------------------------------------------------------------
// Prep: features -> featT [px][32] fp16; weights -> Wt[n][k] fp16.
// W1 cols permuted col=k*32+c; cols 288..291 = rel/cell rows; 292..319 = 0.
// ---------------------------------------------------------------------------
__global__ void liif_prep(const float* __restrict__ feat,
                          const float* __restrict__ w1, const float* __restrict__ w2,
                          const float* __restrict__ w3, const float* __restrict__ w4,
                          const float* __restrict__ w5,
                          _Float16* __restrict__ featT,
                          _Float16* __restrict__ wt1, _Float16* __restrict__ wt2,
                          _Float16* __restrict__ wt3, _Float16* __restrict__ wt4,
                          _Float16* __restrict__ wt5) {
  const int blk = blockIdx.x, tid = threadIdx.x;
  if (blk < 256) {                         // featT: thread = 1 px, 64 B contig write
    const int px = blk * 256 + tid;
    _Float16 v[32];
#pragma unroll
    for (int c = 0; c < 32; ++c) v[c] = (_Float16)feat[(c << 16) + px];
    half8* dst = (half8*)(featT + px * 32);
#pragma unroll
    for (int j = 0; j < 4; ++j) dst[j] = *(half8*)(v + j * 8);
    return;
  }
  int i = (blk - 256) * 256 + tid;
  if (i < 81920) {                         // wt1: [256][320]
    const int n = i / 320, kcol = i % 320;
    float v = 0.f;
    if (kcol < 288) {
      const int k = kcol >> 5, c = kcol & 31;
      v = w1[(c * 9 + k) * 256 + n];
    } else if (kcol < 292) {
      v = w1[kcol * 256 + n];
    }
    wt1[i] = (_Float16)v;
    return;
  }
  i -= 81920;
  if (i < 196608) {                        // wt2..wt4: [256][256]
    const int li = i >> 16, r = i & 65535;
    const int n = r >> 8, k = r & 255;
    const float* w = (li == 0) ? w2 : ((li == 1) ? w3 : w4);
    _Float16* wt = (li == 0) ? wt2 : ((li == 1) ? wt3 : wt4);
    wt[r] = (_Float16)w[k * 256 + n];
    return;
  }
  i -= 196608;
  if (i < 4096) {                          // wt5: [16][256], rows 3..15 zero
    const int n = i >> 8, k = i & 255;
    wt5[i] = (n < 3) ? (_Float16)w5[k * 3 + n] : (_Float16)0.f;
  }
}

// per-row geometry (exact-rounded to match reference)
__device__ __forceinline__ void row_params(int r, const float* __restrict__ loc,
                                           const float* __restrict__ cell,
                                           int& iy, int& ix, float& rel0v, float& rel1v,
                                           float& c0v, float& c1v) {
  const int q = r >> 2, s = r & 3;
  const float loc0 = loc[q * 2 + 0], loc1 = loc[q * 2 + 1];
  const float shy = (s & 2) ? 1.f : -1.f;
  const float shx = (s & 1) ? 1.f : -1.f;
  const float rxy = 1.f / 256.f;
  float l0 = __fadd_rn(loc0 + shy * rxy, 1e-6f);
  float l1 = __fadd_rn(loc1 + shx * rxy, 1e-6f);
  const float lo = -1.f + 1e-6f, hi = 1.f - 1e-6f;
  l0 = fminf(fmaxf(l0, lo), hi);
  l1 = fminf(fmaxf(l1, lo), hi);
  iy = (int)rintf(__fmul_rn(__fadd_rn(__fmul_rn(__fadd_rn(l0, 1.f), 256.f), -1.f), 0.5f));
  ix = (int)rintf(__fmul_rn(__fadd_rn(__fmul_rn(__fadd_rn(l1, 1.f), 256.f), -1.f), 0.5f));
  iy = min(max(iy, 0), 255);
  ix = min(max(ix, 0), 255);
  const float qy = -1.f + (float)(2 * iy + 1) * (1.f / 256.f);
  const float qx = -1.f + (float)(2 * ix + 1) * (1.f / 256.f);
  rel0v = __fmul_rn(__fsub_rn(loc0, qy), 256.f);
  rel1v = __fmul_rn(__fsub_rn(loc1, qx), 256.f);
  c0v = cell[q * 2 + 0] * 256.f;
  c1v = cell[q * 2 + 1] * 256.f;
}

// ---------------------------------------------------------------------------
// One layer: acc[mt][nt] += Wt-frag (A, m=feature) x act-frag (B, n=row).
// A streams from L2, B from XOR-swizzled LDS. 32 MFMAs per k-step per wave.
// ---------------------------------------------------------------------------
template <int NSTEPS, int KW>
__device__ __forceinline__ void layer_mm(const _Float16* __restrict__ wt,
                                         f32x4 acc[4][8],
                                         const _Float16* sA, int w, int lane) {
  const int ln = lane & 15, qd = lane >> 4, e = ln & 7;
  const _Float16* ab[4];
  const _Float16* bb[8];
#pragma unroll
  for (int mt = 0; mt < 4; ++mt)
    ab[mt] = wt + (w * 64 + mt * 16 + ln) * KW + qd * 8;
#pragma unroll
  for (int nt = 0; nt < 8; ++nt)
    bb[nt] = sA + (nt * 16 + ln) * SA;      // (nt*16+ln)&7 == ln&7
#pragma unroll
  for (int st = 0; st < NSTEPS; ++st) {
    const int off = ((((st << 2) | qd) ^ e) << 3);
    half8 a[4], b[8];
#pragma unroll
    for (int mt = 0; mt < 4; ++mt) a[mt] = *(const half8*)(ab[mt] + st * 32);
#pragma unroll
    for (int nt = 0; nt < 8; ++nt) b[nt] = *(const half8*)(bb[nt] + off);
#pragma unroll
    for (int mt = 0; mt < 4; ++mt)
#pragma unroll
      for (int nt = 0; nt < 8; ++nt)
        acc[mt][nt] =
            __builtin_amdgcn_mfma_f32_16x16x32_f16(a[mt], b[nt], acc[mt][nt], 0, 0, 0);
  }
}

// bias + ReLU, write act back (in-place) as half4 b64 stores, swizzled.
__device__ __forceinline__ void epilogue_relu(f32x4 acc[4][8], _Float16* sA,
                                              const float* __restrict__ bias,
                                              int w, int lane) {
  __syncthreads();                          // all waves done reading this layer's act
  const int ln = lane & 15, q4 = (lane >> 4) << 2;
#pragma unroll
  for (int mt = 0; mt < 4; ++mt) {
    const int f = w * 64 + mt * 16 + q4;    // 4 consecutive output features
    const f32x4 bv = *(const f32x4*)(bias + f);
    const int chunk = f >> 3;
#pragma unroll
    for (int nt = 0; nt < 8; ++nt) {
      const int row = nt * 16 + ln;
      half4 h;
#pragma unroll
      for (int r = 0; r < 4; ++r) {
        h[r] = (_Float16)fmaxf(acc[mt][nt][r] + bv[r], 0.f);
        acc[mt][nt][r] = 0.f;
      }
      const int pos = chunk ^ (row & 7);
      *(half4*)(sA + row * SA + pos * 8 + (f & 7)) = h;
    }
  }
  __syncthreads();                          // next layer reads after all writes
}

// ---------------------------------------------------------------------------
// Main fused kernel: 1 block = 128 rows = 32 queries; LDS = 80 KB act buffer.
// ---------------------------------------------------------------------------
__global__ __launch_bounds__(256, 2) void liif_main(
    const _Float16* __restrict__ featT,
    const float* __restrict__ loc, const float* __restrict__ cell,
    const float* __restrict__ b1, const float* __restrict__ b2,
    const float* __restrict__ b3, const float* __restrict__ b4,
    const float* __restrict__ b5,
    const _Float16* __restrict__ wt1, const _Float16* __restrict__ wt2,
    const _Float16* __restrict__ wt3, const _Float16* __restrict__ wt4,
    const _Float16* __restrict__ wt5,
    float* __restrict__ out) {
  extern __shared__ __align__(16) _Float16 sAct[];

  const int tid = threadIdx.x;
  const int w = tid >> 6, lane = tid & 63;
  const int blk = blockIdx.x;

  // ---- gather: thread = (row, half-of-channels); params computed in-regs ----
  {
    const int row = tid >> 1, part = tid & 1;
    int iy, ix; float rel0v, rel1v, c0v, c1v;
    row_params(blk * MROW + row, loc, cell, iy, ix, rel0v, rel1v, c0v, c1v);
    const int y0 = (iy == 0) ? 1 : iy - 1;
    const int y2 = (iy == 255) ? 254 : iy + 1;
    const int x0 = (ix == 0) ? 1 : ix - 1;
    const int x2 = (ix == 255) ? 254 : ix + 1;
    _Float16* arow = sAct + row * SA;
    const int eor = row & 7;
#pragma unroll
    for (int k = 0; k < 9; ++k) {
      const int dy = k / 3, dx = k % 3;
      const int y = (dy == 0) ? y0 : ((dy == 1) ? iy : y2);
      const int x = (dx == 0) ? x0 : ((dx == 1) ? ix : x2);
      const half8* src = (const half8*)(featT + ((y << 8) + x) * 32 + part * 16);
#pragma unroll
      for (int j = 0; j < 2; ++j) {
        const int pos = (k * 4 + part * 2 + j) ^ eor;
        *(half8*)(arow + pos * 8) = src[j];
      }
    }
    // tail chunks 36..39 (cols 288..319): rel/cell + zero pad
#pragma unroll
    for (int j = 0; j < 2; ++j) {
      half8 tv = {};
      if (part == 0 && j == 0) {
        tv[0] = (_Float16)rel0v;
        tv[1] = (_Float16)rel1v;
        tv[2] = (_Float16)c0v;
        tv[3] = (_Float16)c1v;
      }
      const int pos = (36 + part * 2 + j) ^ eor;
      *(half8*)(arow + pos * 8) = tv;
    }
  }

  f32x4 acc[4][8];
#pragma unroll
  for (int mt = 0; mt < 4; ++mt)
#pragma unroll
    for (int nt = 0; nt < 8; ++nt)
      acc[mt][nt] = (f32x4){0.f, 0.f, 0.f, 0.f};

  __syncthreads();

  // ---- MLP layers 1..4 ----
  layer_mm<10, 320>(wt1, acc, sAct, w, lane);
  epilogue_relu(acc, sAct, b1, w, lane);
  layer_mm<8, 256>(wt2, acc, sAct, w, lane);
  epilogue_relu(acc, sAct, b2, w, lane);
  layer_mm<8, 256>(wt3, acc, sAct, w, lane);
  epilogue_relu(acc, sAct, b3, w, lane);
  layer_mm<8, 256>(wt4, acc, sAct, w, lane);
  epilogue_relu(acc, sAct, b4, w, lane);

  // ---- layer 5 (16x256) + area combine; wave w owns rows w*32..w*32+31 ----
  {
    const int ln = lane & 15, qd = lane >> 4, e = ln & 7;
#pragma unroll
    for (int nt = 0; nt < 2; ++nt) {
      f32x4 a5 = {0.f, 0.f, 0.f, 0.f};
      const _Float16* abp = wt5 + ln * 256 + qd * 8;
      const _Float16* bbp = sAct + (w * 32 + nt * 16 + ln) * SA;  // &7 == ln&7
#pragma unroll
      for (int st = 0; st < 8; ++st) {
        const int off = ((((st << 2) | qd) ^ e) << 3);
        const half8 a = *(const half8*)(abp + st * 32);
        const half8 b = *(const half8*)(bbp + off);
        a5 = __builtin_amdgcn_mfma_f32_16x16x32_f16(a, b, a5, 0, 0, 0);
      }
      // combine weight for this lane's row (recomputed; shfl within 4-groups)
      int iy, ix; float rel0v, rel1v, c0v, c1v;
      row_params(blk * MROW + w * 32 + nt * 16 + ln, loc, cell,
                 iy, ix, rel0v, rel1v, c0v, c1v);
      const float area = fabsf(rel0v * rel1v) + 1e-9f;
      float t = area + __shfl_xor(area, 1);
      const float tot = t + __shfl_xor(t, 2);
      const float asw = __shfl_xor(area, 3);
      const float wr = asw / tot;
      float v0 = (a5[0] + b5[0]) * wr;
      float v1 = (a5[1] + b5[1]) * wr;
      float v2 = (a5[2] + b5[2]) * wr;
      v0 += __shfl_xor(v0, 1); v0 += __shfl_xor(v0, 2);
      v1 += __shfl_xor(v1, 1); v1 += __shfl_xor(v1, 2);
      v2 += __shfl_xor(v2, 1); v2 += __shfl_xor(v2, 2);
      if (qd == 0 && (ln & 3) == 0) {
        const int q = blk * 32 + w * 8 + nt * 4 + (ln >> 2);
        out[q * 3 + 0] = v0;
        out[q * 3 + 1] = v1;
        out[q * 3 + 2] = v2;
      }
    }
  }
}

// ---------------------------------------------------------------------------
extern "C" void kernel_launch(void* const* d_in, const int* in_sizes, int n_in,
                              void* d_out, int out_size, void* d_ws, size_t ws_size,
                              hipStream_t stream) {
  (void)in_sizes; (void)n_in; (void)out_size; (void)ws_size;
  const float* feat = (const float*)d_in[0];
  const float* loc  = (const float*)d_in[1];
  const float* cell = (const float*)d_in[2];
  const float* w1 = (const float*)d_in[3];  const float* b1 = (const float*)d_in[4];
  const float* w2 = (const float*)d_in[5];  const float* b2 = (const float*)d_in[6];
  const float* w3 = (const float*)d_in[7];  const float* b3 = (const float*)d_in[8];
  const float* w4 = (const float*)d_in[9];  const float* b4 = (const float*)d_in[10];
  const float* w5 = (const float*)d_in[11]; const float* b5 = (const float*)d_in[12];

  char* ws = (char*)d_ws;
  _Float16* featT = (_Float16*)(ws);                    // 4,194,304 B
  _Float16* wt1 = (_Float16*)(ws + 4194304);            //   163,840 B [256][320]
  _Float16* wt2 = (_Float16*)(ws + 4358144);            //   131,072 B [256][256]
  _Float16* wt3 = (_Float16*)(ws + 4489216);            //   131,072 B
  _Float16* wt4 = (_Float16*)(ws + 4620288);            //   131,072 B
  _Float16* wt5 = (_Float16*)(ws + 4751360);            //     8,192 B [16][256]

  liif_prep<<<1360, 256, 0, stream>>>(feat, w1, w2, w3, w4, w5,
                                      featT, wt1, wt2, wt3, wt4, wt5);
  liif_main<<<2048, 256, MROW * SA * 2, stream>>>(featT, loc, cell,
                                                  b1, b2, b3, b4, b5,
                                                  wt1, wt2, wt3, wt4, wt5,
                                                  (float*)d_out);
}